// Round 7
// baseline (2269.269 us; speedup 1.0000x reference)
//
#include <hip/hip_runtime.h>
#include <stdint.h>

#define B_ 32
#define S_ 512
#define I_ 256
#define H_ 512
#define OUTW 1024
#define OUTS_ELEMS (B_*S_*OUTW)   // 16777216

typedef _Float16 f16;
typedef _Float16 half2_t __attribute__((ext_vector_type(2)));

__device__ __forceinline__ float fdot2(uint32_t a, uint32_t b, float c){
#if __has_builtin(__builtin_amdgcn_fdot2)
  return __builtin_amdgcn_fdot2(__builtin_bit_cast(half2_t, a),
                                __builtin_bit_cast(half2_t, b), c, false);
#else
  half2_t ha = __builtin_bit_cast(half2_t, a);
  half2_t hb = __builtin_bit_cast(half2_t, b);
  return c + (float)ha.x*(float)hb.x + (float)ha.y*(float)hb.y;
#endif
}

__device__ __forceinline__ uint32_t packf16(float x, float y){
  union { f16 h[2]; uint32_t u; } z;
  z.h[0] = (f16)x; z.h[1] = (f16)y;
  return z.u;
}

template<int CTRL>
__device__ __forceinline__ float dpp_xor_add(float x){
  int v = __builtin_amdgcn_update_dpp(0, __float_as_int(x), CTRL, 0xF, 0xF, true);
  return x + __int_as_float(v);
}

// 8-lane (sl) reduce of 4 accs; lane gets total for acc index (sl&3)
__device__ __forceinline__ float reduce8(float a0, float a1, float a2, float a3, int k3){
  a0 = dpp_xor_add<0xB1>(a0); a1 = dpp_xor_add<0xB1>(a1);
  a2 = dpp_xor_add<0xB1>(a2); a3 = dpp_xor_add<0xB1>(a3);
  a0 = dpp_xor_add<0x4E>(a0); a1 = dpp_xor_add<0x4E>(a1);
  a2 = dpp_xor_add<0x4E>(a2); a3 = dpp_xor_add<0x4E>(a3);
  float own = (k3==0)?a0:(k3==1)?a1:(k3==2)?a2:a3;
  return own + __shfl_xor(own, 4);
}

// ---------------------------------------------------------------------------
// P0: W_hh fp32 -> f16 into d_ws
// ---------------------------------------------------------------------------
__global__ __launch_bounds__(256) void cvt_w_kernel(const float* __restrict__ wf,
                                                    const float* __restrict__ wb,
                                                    f16* __restrict__ out){
  int i = blockIdx.x*256 + threadIdx.x;
  const float* src = (i < 32768) ? wf : wb;
  int base = (i & 32767) * 8;
  float4 a = *(const float4*)(src + base);
  float4 c = *(const float4*)(src + base + 4);
  uint4 o;
  o.x = packf16(a.x, a.y); o.y = packf16(a.z, a.w);
  o.z = packf16(c.x, c.y); o.w = packf16(c.z, c.w);
  *(uint4*)(out + (size_t)i*8) = o;
}

// ---------------------------------------------------------------------------
// P1: xp staged into d_out (read once by rnn, then overwritten with h).
// ---------------------------------------------------------------------------
#define PTM 128
#define PTN 64
#define PTK 32
__global__ __launch_bounds__(256) void proj_kernel(
    const float* __restrict__ x,
    const float* __restrict__ wihf, const float* __restrict__ wihb,
    const float* __restrict__ bihf, const float* __restrict__ bhhf,
    const float* __restrict__ bihb, const float* __restrict__ bhhb,
    float* __restrict__ out)
{
  __shared__ float As[PTK][132];
  __shared__ float Bs[PTK][68];
  const int tid = threadIdx.x;
  const int row0 = blockIdx.x * PTM;
  const int j0   = blockIdx.y * PTN;
  const int dir  = (j0 >= 512) ? 1 : 0;
  const int jl0  = j0 - dir*512;
  const float* wih = dir ? wihb : wihf;
  const float* bi  = dir ? bihb : bihf;
  const float* bh  = dir ? bhhb : bhhf;

  const int ty = tid >> 4, tx = tid & 15;
  float acc[8][4];
#pragma unroll
  for (int i=0;i<8;i++)
#pragma unroll
    for (int j=0;j<4;j++) acc[i][j] = 0.f;

  float bias[4];
#pragma unroll
  for (int jj=0;jj<4;jj++){ int jl = jl0 + tx*4 + jj; bias[jj] = bi[jl] + bh[jl]; }

  for (int k0 = 0; k0 < I_; k0 += PTK){
    {
      int r = tid >> 1, kh = (tid & 1) * 16;
      int rg = row0 + r; int bb = rg & 31, tt = rg >> 5;
      const float* ap = x + ((size_t)bb*S_ + tt)*I_ + k0 + kh;
#pragma unroll
      for (int u=0;u<4;u++){
        float4 v = *(const float4*)(ap + u*4);
        As[kh+u*4+0][r] = v.x; As[kh+u*4+1][r] = v.y;
        As[kh+u*4+2][r] = v.z; As[kh+u*4+3][r] = v.w;
      }
    }
    {
      int jr = tid >> 2, kh = (tid & 3) * 8;
      const float* bp = wih + (size_t)(jl0 + jr)*I_ + k0 + kh;
#pragma unroll
      for (int u=0;u<2;u++){
        float4 v = *(const float4*)(bp + u*4);
        Bs[kh+u*4+0][jr] = v.x; Bs[kh+u*4+1][jr] = v.y;
        Bs[kh+u*4+2][jr] = v.z; Bs[kh+u*4+3][jr] = v.w;
      }
    }
    __syncthreads();
#pragma unroll 8
    for (int kk=0; kk<PTK; ++kk){
      const float4 a0 = *(const float4*)&As[kk][ty*8+0];
      const float4 a1 = *(const float4*)&As[kk][ty*8+4];
      const float4 bq = *(const float4*)&Bs[kk][tx*4];
      const float av[8] = {a0.x,a0.y,a0.z,a0.w,a1.x,a1.y,a1.z,a1.w};
      const float bv[4] = {bq.x,bq.y,bq.z,bq.w};
#pragma unroll
      for (int i=0;i<8;i++)
#pragma unroll
        for (int j=0;j<4;j++) acc[i][j] = fmaf(av[i], bv[j], acc[i][j]);
    }
    __syncthreads();
  }
#pragma unroll
  for (int i=0;i<8;i++){
    int rg = row0 + ty*8 + i; int bb = rg & 31, tt = rg >> 5;
    float* op = out + ((size_t)bb*S_ + tt)*OUTW + j0 + tx*4;
    float4 v = {acc[i][0]+bias[0], acc[i][1]+bias[1], acc[i][2]+bias[2], acc[i][3]+bias[3]};
    *(float4*)op = v;
  }
}

// ---------------------------------------------------------------------------
// R: 8-way k-split, 2 chains per CU, W in LDS (64 KB, bank-uniform layout).
// Blocks: G = blk&31 (group: dir=G>>4, batches b0=(G&15)*2, b0+1),
//         q = blk>>5 (k-slice). Group's 8 blocks {G+32q} -> same XCD.
// CU q owns k-cols AND finalize-rows [q*64,(q+1)*64): its next-step h is
// exactly what it finalized -> no h exchange; only tagged f16 partials.
// Lane: sl=tid&7 (k = q*64+sl*8+[0,8)), jr=tid>>3 in [0,128); rows jr+128m.
// Per step/lane: 4 ds_read_b128 W (shared by both chains) + 2 h; 32 fdot2;
// 2 reduce8; publish (sl<4: one row each, incl. own rows) / owner spins on
// a uniform 8 tagged dwords per chain. One barrier/step.
// ---------------------------------------------------------------------------
#define WLDS 65536
#define LDS_TOTAL (WLDS + 512)
#define MAIL_OFF_U32 (1u<<18)          // W f16 = 1 MB = 2^18 u32
#define MAIL_U32     (64*8*2*8*64)     // [chain][dst][parity][src][64] = 2 MB
#define MAIL_BYTES   (MAIL_U32*4)

__global__ __launch_bounds__(1024) void rnn_kernel(
    const f16* __restrict__ Wall,   // [2][512][512] f16
    const float* __restrict__ h0,   // [2][32][512]
    float* dout, uint32_t* mailbase)
{
  extern __shared__ char lds[];
  const int tid = threadIdx.x;
  const int G   = blockIdx.x & 31;        // group
  const int q   = blockIdx.x >> 5;        // k-slice in [0,8)
  const int dir = G >> 4;
  const int b0  = (G & 15) * 2;
  const int sl  = tid & 7;
  const int jr  = tid >> 3;               // [0,128)
  const int k3  = sl & 3;

  const f16* Wd = Wall + (size_t)dir * (H_*(size_t)H_);

  // ---- stage W block: rows 0..511, k-cols [q*64,+64) -> lds[r*128 + kl*2]
  {
    const int r = tid >> 1, hf = tid & 1;
    const f16* src = Wd + (size_t)r*H_ + q*64 + hf*32;
    char* dst = lds + r*128 + hf*64;
#pragma unroll
    for (int i=0;i<4;i++)
      *(uint4*)(dst + i*16) = *(const uint4*)(src + i*8);
  }
  // ---- stage h0 (both chains, parity 0): h[c][P] at WLDS + (c*2+P)*128
  if (tid < 128){
    const int c = tid >> 6, k = tid & 63;
    *(f16*)(lds + WLDS + (c*2+0)*128 + k*2) =
        (f16)h0[((size_t)dir*B_ + (b0+c))*H_ + q*64 + k];
  }
  __syncthreads();

  // ownership / publishing geometry
  const bool owner = (sl == (q>>1)) && ((jr>>6) == (q&1));
  const int  myrow = jr + 128*(q>>1);          // owner's global row
  const int  lr    = jr & 63;                  // row index within 64-block
  const int  pdst  = (jr>>6) + 2*sl;           // publish dst CU (valid sl<4)
  const int  ch0   = G*2, ch1 = G*2 + 1;

  float* outs0 = dout + (size_t)(b0  )*(S_*OUTW);
  float* outs1 = dout + (size_t)(b0+1)*(S_*OUTW);
  const int col = dir*512 + myrow;
  float* hn0 = dout + (size_t)OUTS_ELEMS + ((size_t)dir*B_ + b0  )*H_;
  float* hn1 = dout + (size_t)OUTS_ELEMS + ((size_t)dir*B_ + b0+1)*H_;
  uint32_t* mb = mailbase;

  for (int s=0; s<S_; ++s){
    const int P = s & 1;
    const int t = dir ? (S_-1-s) : s;
    const uint32_t tag = (uint32_t)(s+1);
    float* xo0 = outs0 + (size_t)t*OUTW;
    float* xo1 = outs1 + (size_t)t*OUTW;
    float xp0 = 0.f, xp1 = 0.f;
    if (owner){ xp0 = xo0[col]; xp1 = xo1[col]; }   // long-latency, hidden

    // W fragments (shared by both chains): rows jr+128m, 16B each
    const uint4 w0 = *(const uint4*)(lds + (jr      )*128 + sl*16);
    const uint4 w1 = *(const uint4*)(lds + (jr + 128)*128 + sl*16);
    const uint4 w2 = *(const uint4*)(lds + (jr + 256)*128 + sl*16);
    const uint4 w3 = *(const uint4*)(lds + (jr + 384)*128 + sl*16);

    // ---- chain 0: compute + publish ASAP
    {
      const uint4 hv = *(const uint4*)(lds + WLDS + (0*2+P)*128 + sl*16);
      float a0=0.f,a1=0.f,a2=0.f,a3=0.f;
      a0=fdot2(w0.x,hv.x,a0); a0=fdot2(w0.y,hv.y,a0); a0=fdot2(w0.z,hv.z,a0); a0=fdot2(w0.w,hv.w,a0);
      a1=fdot2(w1.x,hv.x,a1); a1=fdot2(w1.y,hv.y,a1); a1=fdot2(w1.z,hv.z,a1); a1=fdot2(w1.w,hv.w,a1);
      a2=fdot2(w2.x,hv.x,a2); a2=fdot2(w2.y,hv.y,a2); a2=fdot2(w2.z,hv.z,a2); a2=fdot2(w2.w,hv.w,a2);
      a3=fdot2(w3.x,hv.x,a3); a3=fdot2(w3.y,hv.y,a3); a3=fdot2(w3.z,hv.z,a3); a3=fdot2(w3.w,hv.w,a3);
      float tot = reduce8(a0,a1,a2,a3,k3);
      if (sl < 4){
        uint16_t pb = __builtin_bit_cast(uint16_t, (f16)tot);
        size_t idx = ((((size_t)ch0*8 + pdst)*2 + P)*8 + q)*64 + lr;
        __hip_atomic_store(&mb[idx], ((uint32_t)pb << 16) | tag,
                           __ATOMIC_RELAXED, __HIP_MEMORY_SCOPE_AGENT);
      }
    }
    // ---- chain 1: compute + publish (partner RT for c0 hides under this)
    {
      const uint4 hv = *(const uint4*)(lds + WLDS + (1*2+P)*128 + sl*16);
      float a0=0.f,a1=0.f,a2=0.f,a3=0.f;
      a0=fdot2(w0.x,hv.x,a0); a0=fdot2(w0.y,hv.y,a0); a0=fdot2(w0.z,hv.z,a0); a0=fdot2(w0.w,hv.w,a0);
      a1=fdot2(w1.x,hv.x,a1); a1=fdot2(w1.y,hv.y,a1); a1=fdot2(w1.z,hv.z,a1); a1=fdot2(w1.w,hv.w,a1);
      a2=fdot2(w2.x,hv.x,a2); a2=fdot2(w2.y,hv.y,a2); a2=fdot2(w2.z,hv.z,a2); a2=fdot2(w2.w,hv.w,a2);
      a3=fdot2(w3.x,hv.x,a3); a3=fdot2(w3.y,hv.y,a3); a3=fdot2(w3.z,hv.z,a3); a3=fdot2(w3.w,hv.w,a3);
      float tot = reduce8(a0,a1,a2,a3,k3);
      if (sl < 4){
        uint16_t pb = __builtin_bit_cast(uint16_t, (f16)tot);
        size_t idx = ((((size_t)ch1*8 + pdst)*2 + P)*8 + q)*64 + lr;
        __hip_atomic_store(&mb[idx], ((uint32_t)pb << 16) | tag,
                           __ATOMIC_RELAXED, __HIP_MEMORY_SCOPE_AGENT);
      }
    }
    // ---- finalize both chains: spin on 8 tagged dwords each (incl. own)
    if (owner){
      {
        uint32_t* rb = mb + ((((size_t)ch0*8 + q)*2 + P)*8)*64 + lr;
        uint32_t v0,v1,v2,v3,v4,v5,v6,v7;
        do {
          v0=__hip_atomic_load(rb+  0,__ATOMIC_RELAXED,__HIP_MEMORY_SCOPE_AGENT);
          v1=__hip_atomic_load(rb+ 64,__ATOMIC_RELAXED,__HIP_MEMORY_SCOPE_AGENT);
          v2=__hip_atomic_load(rb+128,__ATOMIC_RELAXED,__HIP_MEMORY_SCOPE_AGENT);
          v3=__hip_atomic_load(rb+192,__ATOMIC_RELAXED,__HIP_MEMORY_SCOPE_AGENT);
          v4=__hip_atomic_load(rb+256,__ATOMIC_RELAXED,__HIP_MEMORY_SCOPE_AGENT);
          v5=__hip_atomic_load(rb+320,__ATOMIC_RELAXED,__HIP_MEMORY_SCOPE_AGENT);
          v6=__hip_atomic_load(rb+384,__ATOMIC_RELAXED,__HIP_MEMORY_SCOPE_AGENT);
          v7=__hip_atomic_load(rb+448,__ATOMIC_RELAXED,__HIP_MEMORY_SCOPE_AGENT);
        } while ((((v0^tag)|(v1^tag)|(v2^tag)|(v3^tag)|
                   (v4^tag)|(v5^tag)|(v6^tag)|(v7^tag)) & 0xffffu) != 0u);
        float rem = (float)__builtin_bit_cast(f16,(uint16_t)(v0>>16))
                  + (float)__builtin_bit_cast(f16,(uint16_t)(v1>>16))
                  + (float)__builtin_bit_cast(f16,(uint16_t)(v2>>16))
                  + (float)__builtin_bit_cast(f16,(uint16_t)(v3>>16))
                  + (float)__builtin_bit_cast(f16,(uint16_t)(v4>>16))
                  + (float)__builtin_bit_cast(f16,(uint16_t)(v5>>16))
                  + (float)__builtin_bit_cast(f16,(uint16_t)(v6>>16))
                  + (float)__builtin_bit_cast(f16,(uint16_t)(v7>>16));
        float h = fmaxf(xp0 + rem, 0.f);
        xo0[col] = h;
        if (s == S_-1) hn0[myrow] = h;
        *(f16*)(lds + WLDS + (0*2+(P^1))*128 + lr*2) = (f16)h;
      }
      {
        uint32_t* rb = mb + ((((size_t)ch1*8 + q)*2 + P)*8)*64 + lr;
        uint32_t v0,v1,v2,v3,v4,v5,v6,v7;
        do {
          v0=__hip_atomic_load(rb+  0,__ATOMIC_RELAXED,__HIP_MEMORY_SCOPE_AGENT);
          v1=__hip_atomic_load(rb+ 64,__ATOMIC_RELAXED,__HIP_MEMORY_SCOPE_AGENT);
          v2=__hip_atomic_load(rb+128,__ATOMIC_RELAXED,__HIP_MEMORY_SCOPE_AGENT);
          v3=__hip_atomic_load(rb+192,__ATOMIC_RELAXED,__HIP_MEMORY_SCOPE_AGENT);
          v4=__hip_atomic_load(rb+256,__ATOMIC_RELAXED,__HIP_MEMORY_SCOPE_AGENT);
          v5=__hip_atomic_load(rb+320,__ATOMIC_RELAXED,__HIP_MEMORY_SCOPE_AGENT);
          v6=__hip_atomic_load(rb+384,__ATOMIC_RELAXED,__HIP_MEMORY_SCOPE_AGENT);
          v7=__hip_atomic_load(rb+448,__ATOMIC_RELAXED,__HIP_MEMORY_SCOPE_AGENT);
        } while ((((v0^tag)|(v1^tag)|(v2^tag)|(v3^tag)|
                   (v4^tag)|(v5^tag)|(v6^tag)|(v7^tag)) & 0xffffu) != 0u);
        float rem = (float)__builtin_bit_cast(f16,(uint16_t)(v0>>16))
                  + (float)__builtin_bit_cast(f16,(uint16_t)(v1>>16))
                  + (float)__builtin_bit_cast(f16,(uint16_t)(v2>>16))
                  + (float)__builtin_bit_cast(f16,(uint16_t)(v3>>16))
                  + (float)__builtin_bit_cast(f16,(uint16_t)(v4>>16))
                  + (float)__builtin_bit_cast(f16,(uint16_t)(v5>>16))
                  + (float)__builtin_bit_cast(f16,(uint16_t)(v6>>16))
                  + (float)__builtin_bit_cast(f16,(uint16_t)(v7>>16));
        float h = fmaxf(xp1 + rem, 0.f);
        xo1[col] = h;
        if (s == S_-1) hn1[myrow] = h;
        *(f16*)(lds + WLDS + (1*2+(P^1))*128 + lr*2) = (f16)h;
      }
    }
    asm volatile("s_waitcnt lgkmcnt(0)" ::: "memory");
    __builtin_amdgcn_s_barrier();
  }
}

// ---------------------------------------------------------------------------
extern "C" void kernel_launch(void* const* d_in, const int* in_sizes, int n_in,
                              void* d_out, int out_size, void* d_ws, size_t ws_size,
                              hipStream_t stream){
  const float* x    = (const float*)d_in[0];
  const float* h0   = (const float*)d_in[1];
  const float* wihf = (const float*)d_in[2];
  const float* whhf = (const float*)d_in[3];
  const float* bihf = (const float*)d_in[4];
  const float* bhhf = (const float*)d_in[5];
  const float* wihb = (const float*)d_in[6];
  const float* whhb = (const float*)d_in[7];
  const float* bihb = (const float*)d_in[8];
  const float* bhhb = (const float*)d_in[9];
  float* out = (float*)d_out;
  f16* wf16 = (f16*)d_ws;                            // 1 MB
  uint32_t* mail = (uint32_t*)d_ws + MAIL_OFF_U32;   // 2 MB

  hipMemsetAsync((void*)mail, 0, MAIL_BYTES, stream);  // kill stale tags across replays
  cvt_w_kernel<<<256, 256, 0, stream>>>(whhf, whhb, wf16);
  proj_kernel<<<dim3(128, 16), 256, 0, stream>>>(x, wihf, wihb, bihf, bhhf, bihb, bhhb, out);
  (void)hipFuncSetAttribute((const void*)rnn_kernel,
                            hipFuncAttributeMaxDynamicSharedMemorySize, LDS_TOTAL);
  rnn_kernel<<<256, 1024, LDS_TOTAL, stream>>>(wf16, h0, out, mail);
}

// Round 8
// 2025.696 us; speedup vs baseline: 1.1202x; 1.1202x over previous
//
#include <hip/hip_runtime.h>
#include <stdint.h>

#define B_ 32
#define S_ 512
#define I_ 256
#define H_ 512
#define OUTW 1024
#define OUTS_ELEMS (B_*S_*OUTW)   // 16777216

typedef _Float16 f16;
typedef _Float16 half2_t __attribute__((ext_vector_type(2)));

__device__ __forceinline__ float fdot2(uint32_t a, uint32_t b, float c){
#if __has_builtin(__builtin_amdgcn_fdot2)
  return __builtin_amdgcn_fdot2(__builtin_bit_cast(half2_t, a),
                                __builtin_bit_cast(half2_t, b), c, false);
#else
  half2_t ha = __builtin_bit_cast(half2_t, a);
  half2_t hb = __builtin_bit_cast(half2_t, b);
  return c + (float)ha.x*(float)hb.x + (float)ha.y*(float)hb.y;
#endif
}

__device__ __forceinline__ uint32_t packf16(float x, float y){
  union { f16 h[2]; uint32_t u; } z;
  z.h[0] = (f16)x; z.h[1] = (f16)y;
  return z.u;
}

template<int CTRL>
__device__ __forceinline__ float dpp_xor_add(float x){
  int v = __builtin_amdgcn_update_dpp(0, __float_as_int(x), CTRL, 0xF, 0xF, true);
  return x + __int_as_float(v);
}

// 8-lane (sl) reduce of 4 accs; lanes sl and sl^4 both get total for acc (sl&3)
__device__ __forceinline__ float reduce8(float a0, float a1, float a2, float a3, int k3){
  a0 = dpp_xor_add<0xB1>(a0); a1 = dpp_xor_add<0xB1>(a1);
  a2 = dpp_xor_add<0xB1>(a2); a3 = dpp_xor_add<0xB1>(a3);
  a0 = dpp_xor_add<0x4E>(a0); a1 = dpp_xor_add<0x4E>(a1);
  a2 = dpp_xor_add<0x4E>(a2); a3 = dpp_xor_add<0x4E>(a3);
  float own = (k3==0)?a0:(k3==1)?a1:(k3==2)?a2:a3;
  return own + __shfl_xor(own, 4);
}

// ---------------------------------------------------------------------------
// P0: W_hh fp32 -> f16 into d_ws
// ---------------------------------------------------------------------------
__global__ __launch_bounds__(256) void cvt_w_kernel(const float* __restrict__ wf,
                                                    const float* __restrict__ wb,
                                                    f16* __restrict__ out){
  int i = blockIdx.x*256 + threadIdx.x;
  const float* src = (i < 32768) ? wf : wb;
  int base = (i & 32767) * 8;
  float4 a = *(const float4*)(src + base);
  float4 c = *(const float4*)(src + base + 4);
  uint4 o;
  o.x = packf16(a.x, a.y); o.y = packf16(a.z, a.w);
  o.z = packf16(c.x, c.y); o.w = packf16(c.z, c.w);
  *(uint4*)(out + (size_t)i*8) = o;
}

// ---------------------------------------------------------------------------
// P1: xp staged into d_out (read once by rnn, then overwritten with h).
// ---------------------------------------------------------------------------
#define PTM 128
#define PTN 64
#define PTK 32
__global__ __launch_bounds__(256) void proj_kernel(
    const float* __restrict__ x,
    const float* __restrict__ wihf, const float* __restrict__ wihb,
    const float* __restrict__ bihf, const float* __restrict__ bhhf,
    const float* __restrict__ bihb, const float* __restrict__ bhhb,
    float* __restrict__ out)
{
  __shared__ float As[PTK][132];
  __shared__ float Bs[PTK][68];
  const int tid = threadIdx.x;
  const int row0 = blockIdx.x * PTM;
  const int j0   = blockIdx.y * PTN;
  const int dir  = (j0 >= 512) ? 1 : 0;
  const int jl0  = j0 - dir*512;
  const float* wih = dir ? wihb : wihf;
  const float* bi  = dir ? bihb : bihf;
  const float* bh  = dir ? bhhb : bhhf;

  const int ty = tid >> 4, tx = tid & 15;
  float acc[8][4];
#pragma unroll
  for (int i=0;i<8;i++)
#pragma unroll
    for (int j=0;j<4;j++) acc[i][j] = 0.f;

  float bias[4];
#pragma unroll
  for (int jj=0;jj<4;jj++){ int jl = jl0 + tx*4 + jj; bias[jj] = bi[jl] + bh[jl]; }

  for (int k0 = 0; k0 < I_; k0 += PTK){
    {
      int r = tid >> 1, kh = (tid & 1) * 16;
      int rg = row0 + r; int bb = rg & 31, tt = rg >> 5;
      const float* ap = x + ((size_t)bb*S_ + tt)*I_ + k0 + kh;
#pragma unroll
      for (int u=0;u<4;u++){
        float4 v = *(const float4*)(ap + u*4);
        As[kh+u*4+0][r] = v.x; As[kh+u*4+1][r] = v.y;
        As[kh+u*4+2][r] = v.z; As[kh+u*4+3][r] = v.w;
      }
    }
    {
      int jr = tid >> 2, kh = (tid & 3) * 8;
      const float* bp = wih + (size_t)(jl0 + jr)*I_ + k0 + kh;
#pragma unroll
      for (int u=0;u<2;u++){
        float4 v = *(const float4*)(bp + u*4);
        Bs[kh+u*4+0][jr] = v.x; Bs[kh+u*4+1][jr] = v.y;
        Bs[kh+u*4+2][jr] = v.z; Bs[kh+u*4+3][jr] = v.w;
      }
    }
    __syncthreads();
#pragma unroll 8
    for (int kk=0; kk<PTK; ++kk){
      const float4 a0 = *(const float4*)&As[kk][ty*8+0];
      const float4 a1 = *(const float4*)&As[kk][ty*8+4];
      const float4 bq = *(const float4*)&Bs[kk][tx*4];
      const float av[8] = {a0.x,a0.y,a0.z,a0.w,a1.x,a1.y,a1.z,a1.w};
      const float bv[4] = {bq.x,bq.y,bq.z,bq.w};
#pragma unroll
      for (int i=0;i<8;i++)
#pragma unroll
        for (int j=0;j<4;j++) acc[i][j] = fmaf(av[i], bv[j], acc[i][j]);
    }
    __syncthreads();
  }
#pragma unroll
  for (int i=0;i<8;i++){
    int rg = row0 + ty*8 + i; int bb = rg & 31, tt = rg >> 5;
    float* op = out + ((size_t)bb*S_ + tt)*OUTW + j0 + tx*4;
    float4 v = {acc[i][0]+bias[0], acc[i][1]+bias[1], acc[i][2]+bias[2], acc[i][3]+bias[3]};
    *(float4*)op = v;
  }
}

// ---------------------------------------------------------------------------
// R: 8-way k-split, 2 chains per CU, weights in 32 NAMED scalar VGPRs/lane.
// 256 WGs x 512 thr (1 per CU, co-resident). G = blk&31 (dir=G>>4,
// b0=2*(G&15)), q = blk>>5 in [0,8). Group's 8 blocks {G+32q} -> same XCD.
// CU q owns k-cols AND finalize-rows [q*64,(q+1)*64): its next-step h is
// exactly what it finalized -> NO h exchange, only tagged f16 row-totals.
// Lane (sl=tid&7, jr=tid>>3): rows {jr+64m}, k = q*64+sl*8+[0,8) -> 32 W
// dwords (under the empirically observed ~88-VGPR budget at 512 thr).
// Per chain/step: 1 broadcast ds_read_b128 (h), 32 fdot2, 2x reduce8 ->
// lane sl holds total of row jr+64*sl -> publish 1 tagged dword to CU sl
// (self-publish included). Owner lanes (sl==q) spin on 8 uniform dwords.
// One barrier per step.
// ---------------------------------------------------------------------------
#define MAIL_OFF_U32 (1u<<18)          // W f16 = 1 MB = 2^18 u32
#define MAIL_U32     (64*8*2*8*64)     // [chain][dst][parity][src][jr] = 2 MB
#define MAIL_BYTES   (MAIL_U32*4)

#define DECL4(Pn) uint32_t Pn##_0,Pn##_1,Pn##_2,Pn##_3
#define LOAD4(Pn, src) do{ uint4 _v = *(const uint4*)(src); \
  Pn##_0=_v.x; Pn##_1=_v.y; Pn##_2=_v.z; Pn##_3=_v.w; }while(0)
#define KEEP4(Pn) asm volatile("" : \
  "+v"(Pn##_0),"+v"(Pn##_1),"+v"(Pn##_2),"+v"(Pn##_3))
#define DOT4(ACC, Pn, HV) \
  ACC=fdot2(Pn##_0,HV.x,ACC); ACC=fdot2(Pn##_1,HV.y,ACC); \
  ACC=fdot2(Pn##_2,HV.z,ACC); ACC=fdot2(Pn##_3,HV.w,ACC);

__global__ __launch_bounds__(512) void rnn_kernel(
    const f16* __restrict__ Wall,   // [2][512][512] f16
    const float* __restrict__ h0,   // [2][32][512]
    float* dout, uint32_t* mailbase)
{
  __shared__ char lds[512];         // h: [chain 2][parity 2][64 f16]
  const int tid = threadIdx.x;
  const int G   = blockIdx.x & 31;
  const int q   = blockIdx.x >> 5;        // k-slice / owned-row block
  const int dir = G >> 4;
  const int b0  = (G & 15) * 2;
  const int sl  = tid & 7;
  const int jr  = tid >> 3;               // [0,64)
  const int k3  = sl & 3;
  const bool owner = (sl == q);

  const f16* Wd = Wall + (size_t)dir * (H_*(size_t)H_);

  // ---- weights: 8 rows (jr+64m) x 8 f16 (k = q*64 + sl*8) = 32 dwords
  DECL4(W0); DECL4(W1); DECL4(W2); DECL4(W3);
  DECL4(W4); DECL4(W5); DECL4(W6); DECL4(W7);
  {
    const f16* kb = Wd + q*64 + sl*8;
    LOAD4(W0, kb + (size_t)(jr +   0)*H_);
    LOAD4(W1, kb + (size_t)(jr +  64)*H_);
    LOAD4(W2, kb + (size_t)(jr + 128)*H_);
    LOAD4(W3, kb + (size_t)(jr + 192)*H_);
    LOAD4(W4, kb + (size_t)(jr + 256)*H_);
    LOAD4(W5, kb + (size_t)(jr + 320)*H_);
    LOAD4(W6, kb + (size_t)(jr + 384)*H_);
    LOAD4(W7, kb + (size_t)(jr + 448)*H_);
  }
  KEEP4(W0); KEEP4(W1); KEEP4(W2); KEEP4(W3);
  KEEP4(W4); KEEP4(W5); KEEP4(W6); KEEP4(W7);   // one-time anti-remat opacity

  // ---- stage h0 (both chains, parity 0)
  if (tid < 128){
    const int c = tid >> 6, k = tid & 63;
    *(f16*)(lds + (c*2+0)*128 + k*2) =
        (f16)h0[((size_t)dir*B_ + (b0+c))*H_ + q*64 + k];
  }
  __syncthreads();

  const int myrow = jr + 64*q;            // owner's global row
  const int col   = dir*512 + myrow;
  const size_t ch0 = (size_t)(G*2), ch1 = (size_t)(G*2+1);
  float* outs0 = dout + (size_t)(b0  )*(S_*OUTW);
  float* outs1 = dout + (size_t)(b0+1)*(S_*OUTW);
  float* hn0 = dout + (size_t)OUTS_ELEMS + ((size_t)dir*B_ + b0  )*H_;
  float* hn1 = dout + (size_t)OUTS_ELEMS + ((size_t)dir*B_ + b0+1)*H_;
  uint32_t* mb = mailbase;

  for (int s=0; s<S_; ++s){
    const int P = s & 1;
    const int t = dir ? (S_-1-s) : s;
    const uint32_t tag = (uint32_t)(s+1);
    float* xo0 = outs0 + (size_t)t*OUTW;
    float* xo1 = outs1 + (size_t)t*OUTW;
    float xp0 = 0.f, xp1 = 0.f;
    if (owner){ xp0 = xo0[col]; xp1 = xo1[col]; }   // long-latency, hidden

    // ---- chain 0: compute + publish ASAP
    {
      const uint4 hv = *(const uint4*)(lds + (0*2+P)*128 + sl*16);  // broadcast
      float a0=0.f,a1=0.f,a2=0.f,a3=0.f,a4=0.f,a5=0.f,a6=0.f,a7=0.f;
      DOT4(a0,W0,hv) DOT4(a1,W1,hv) DOT4(a2,W2,hv) DOT4(a3,W3,hv)
      DOT4(a4,W4,hv) DOT4(a5,W5,hv) DOT4(a6,W6,hv) DOT4(a7,W7,hv)
      float tlo = reduce8(a0,a1,a2,a3,k3);
      float thi = reduce8(a4,a5,a6,a7,k3);
      float tot = (sl < 4) ? tlo : thi;   // total for row jr + 64*sl
      uint16_t pb = __builtin_bit_cast(uint16_t, (f16)tot);
      size_t idx = (((ch0*8 + sl)*2 + P)*8 + q)*64 + jr;
      __hip_atomic_store(&mb[idx], ((uint32_t)pb << 16) | tag,
                         __ATOMIC_RELAXED, __HIP_MEMORY_SCOPE_AGENT);
    }
    // ---- chain 1: compute + publish (c0 partials fly meanwhile)
    {
      const uint4 hv = *(const uint4*)(lds + (1*2+P)*128 + sl*16);
      float a0=0.f,a1=0.f,a2=0.f,a3=0.f,a4=0.f,a5=0.f,a6=0.f,a7=0.f;
      DOT4(a0,W0,hv) DOT4(a1,W1,hv) DOT4(a2,W2,hv) DOT4(a3,W3,hv)
      DOT4(a4,W4,hv) DOT4(a5,W5,hv) DOT4(a6,W6,hv) DOT4(a7,W7,hv)
      float tlo = reduce8(a0,a1,a2,a3,k3);
      float thi = reduce8(a4,a5,a6,a7,k3);
      float tot = (sl < 4) ? tlo : thi;
      uint16_t pb = __builtin_bit_cast(uint16_t, (f16)tot);
      size_t idx = (((ch1*8 + sl)*2 + P)*8 + q)*64 + jr;
      __hip_atomic_store(&mb[idx], ((uint32_t)pb << 16) | tag,
                         __ATOMIC_RELAXED, __HIP_MEMORY_SCOPE_AGENT);
    }
    // ---- owner finalize: spin on 8 uniform tagged dwords per chain
    if (owner){
      {
        uint32_t* rb = mb + (((ch0*8 + q)*2 + P)*8)*64 + jr;
        uint32_t v0,v1,v2,v3,v4,v5,v6,v7;
        do {
          v0=__hip_atomic_load(rb+  0,__ATOMIC_RELAXED,__HIP_MEMORY_SCOPE_AGENT);
          v1=__hip_atomic_load(rb+ 64,__ATOMIC_RELAXED,__HIP_MEMORY_SCOPE_AGENT);
          v2=__hip_atomic_load(rb+128,__ATOMIC_RELAXED,__HIP_MEMORY_SCOPE_AGENT);
          v3=__hip_atomic_load(rb+192,__ATOMIC_RELAXED,__HIP_MEMORY_SCOPE_AGENT);
          v4=__hip_atomic_load(rb+256,__ATOMIC_RELAXED,__HIP_MEMORY_SCOPE_AGENT);
          v5=__hip_atomic_load(rb+320,__ATOMIC_RELAXED,__HIP_MEMORY_SCOPE_AGENT);
          v6=__hip_atomic_load(rb+384,__ATOMIC_RELAXED,__HIP_MEMORY_SCOPE_AGENT);
          v7=__hip_atomic_load(rb+448,__ATOMIC_RELAXED,__HIP_MEMORY_SCOPE_AGENT);
        } while ((((v0^tag)|(v1^tag)|(v2^tag)|(v3^tag)|
                   (v4^tag)|(v5^tag)|(v6^tag)|(v7^tag)) & 0xffffu) != 0u);
        float rem = (float)__builtin_bit_cast(f16,(uint16_t)(v0>>16))
                  + (float)__builtin_bit_cast(f16,(uint16_t)(v1>>16))
                  + (float)__builtin_bit_cast(f16,(uint16_t)(v2>>16))
                  + (float)__builtin_bit_cast(f16,(uint16_t)(v3>>16))
                  + (float)__builtin_bit_cast(f16,(uint16_t)(v4>>16))
                  + (float)__builtin_bit_cast(f16,(uint16_t)(v5>>16))
                  + (float)__builtin_bit_cast(f16,(uint16_t)(v6>>16))
                  + (float)__builtin_bit_cast(f16,(uint16_t)(v7>>16));
        float h = fmaxf(xp0 + rem, 0.f);
        xo0[col] = h;
        if (s == S_-1) hn0[myrow] = h;
        *(f16*)(lds + (0*2+(P^1))*128 + jr*2) = (f16)h;
      }
      {
        uint32_t* rb = mb + (((ch1*8 + q)*2 + P)*8)*64 + jr;
        uint32_t v0,v1,v2,v3,v4,v5,v6,v7;
        do {
          v0=__hip_atomic_load(rb+  0,__ATOMIC_RELAXED,__HIP_MEMORY_SCOPE_AGENT);
          v1=__hip_atomic_load(rb+ 64,__ATOMIC_RELAXED,__HIP_MEMORY_SCOPE_AGENT);
          v2=__hip_atomic_load(rb+128,__ATOMIC_RELAXED,__HIP_MEMORY_SCOPE_AGENT);
          v3=__hip_atomic_load(rb+192,__ATOMIC_RELAXED,__HIP_MEMORY_SCOPE_AGENT);
          v4=__hip_atomic_load(rb+256,__ATOMIC_RELAXED,__HIP_MEMORY_SCOPE_AGENT);
          v5=__hip_atomic_load(rb+320,__ATOMIC_RELAXED,__HIP_MEMORY_SCOPE_AGENT);
          v6=__hip_atomic_load(rb+384,__ATOMIC_RELAXED,__HIP_MEMORY_SCOPE_AGENT);
          v7=__hip_atomic_load(rb+448,__ATOMIC_RELAXED,__HIP_MEMORY_SCOPE_AGENT);
        } while ((((v0^tag)|(v1^tag)|(v2^tag)|(v3^tag)|
                   (v4^tag)|(v5^tag)|(v6^tag)|(v7^tag)) & 0xffffu) != 0u);
        float rem = (float)__builtin_bit_cast(f16,(uint16_t)(v0>>16))
                  + (float)__builtin_bit_cast(f16,(uint16_t)(v1>>16))
                  + (float)__builtin_bit_cast(f16,(uint16_t)(v2>>16))
                  + (float)__builtin_bit_cast(f16,(uint16_t)(v3>>16))
                  + (float)__builtin_bit_cast(f16,(uint16_t)(v4>>16))
                  + (float)__builtin_bit_cast(f16,(uint16_t)(v5>>16))
                  + (float)__builtin_bit_cast(f16,(uint16_t)(v6>>16))
                  + (float)__builtin_bit_cast(f16,(uint16_t)(v7>>16));
        float h = fmaxf(xp1 + rem, 0.f);
        xo1[col] = h;
        if (s == S_-1) hn1[myrow] = h;
        *(f16*)(lds + (1*2+(P^1))*128 + jr*2) = (f16)h;
      }
    }
    asm volatile("s_waitcnt lgkmcnt(0)" ::: "memory");
    __builtin_amdgcn_s_barrier();
  }
}

// ---------------------------------------------------------------------------
extern "C" void kernel_launch(void* const* d_in, const int* in_sizes, int n_in,
                              void* d_out, int out_size, void* d_ws, size_t ws_size,
                              hipStream_t stream){
  const float* x    = (const float*)d_in[0];
  const float* h0   = (const float*)d_in[1];
  const float* wihf = (const float*)d_in[2];
  const float* whhf = (const float*)d_in[3];
  const float* bihf = (const float*)d_in[4];
  const float* bhhf = (const float*)d_in[5];
  const float* wihb = (const float*)d_in[6];
  const float* whhb = (const float*)d_in[7];
  const float* bihb = (const float*)d_in[8];
  const float* bhhb = (const float*)d_in[9];
  float* out = (float*)d_out;
  f16* wf16 = (f16*)d_ws;                            // 1 MB
  uint32_t* mail = (uint32_t*)d_ws + MAIL_OFF_U32;   // 2 MB

  hipMemsetAsync((void*)mail, 0, MAIL_BYTES, stream);  // kill stale tags across replays
  cvt_w_kernel<<<256, 256, 0, stream>>>(whhf, whhb, wf16);
  proj_kernel<<<dim3(128, 16), 256, 0, stream>>>(x, wihf, wihb, bihf, bhhf, bihb, bhhb, out);
  rnn_kernel<<<256, 512, 0, stream>>>(wf16, h0, out, mail);
}